// Round 1
// baseline (1402.877 us; speedup 1.0000x reference)
//
#include <hip/hip_runtime.h>

#define NN 100000
#define LN_EPS 1e-5f

__device__ __forceinline__ void fma4(float4& a, float s, const float4& w) {
  a.x = fmaf(s, w.x, a.x);
  a.y = fmaf(s, w.y, a.y);
  a.z = fmaf(s, w.z, a.z);
  a.w = fmaf(s, w.w, a.w);
}

// ---------------- CSR build ----------------

__global__ void k_hist(const int* __restrict__ dst, int* __restrict__ deg, int E) {
  int i = blockIdx.x * 256 + threadIdx.x;
  if (i < E) atomicAdd(&deg[dst[i]], 1);
}

__global__ void k_dis(const int* __restrict__ deg, float* __restrict__ dis,
                      float* __restrict__ selfc, int n) {
  int i = blockIdx.x * 256 + threadIdx.x;
  if (i < n) {
    float d = (float)(deg[i] + 1);   // +1 self loop
    dis[i] = rsqrtf(d);
    selfc[i] = 1.0f / d;
  }
}

// block scans 2048 elements (8 per thread); writes local-exclusive scan + block sums
__global__ void k_scanA(const int* __restrict__ deg, int* __restrict__ rp,
                        int* __restrict__ bsum, int n) {
  __shared__ int sh[256];
  int t = threadIdx.x;
  int base = blockIdx.x * 2048 + t * 8;
  int v[8];
  int s = 0;
#pragma unroll
  for (int i = 0; i < 8; ++i) {
    int idx = base + i;
    v[i] = (idx < n) ? deg[idx] : 0;
    s += v[i];
  }
  sh[t] = s;
  __syncthreads();
  for (int d = 1; d < 256; d <<= 1) {
    int add = (t >= d) ? sh[t - d] : 0;
    __syncthreads();
    sh[t] += add;
    __syncthreads();
  }
  int excl = sh[t] - s;
  if (t == 255) bsum[blockIdx.x] = sh[255];
  int run = excl;
#pragma unroll
  for (int i = 0; i < 8; ++i) {
    int idx = base + i;
    if (idx < n) rp[idx] = run;
    run += v[i];
  }
}

// single wave scans the (<=64) block sums in place (exclusive)
__global__ void k_scanB(int* bsum, int nb) {
  int t = threadIdx.x;
  int x = (t < nb) ? bsum[t] : 0;
  int incl = x;
#pragma unroll
  for (int d = 1; d < 64; d <<= 1) {
    int y = __shfl_up(incl, d, 64);
    if (t >= d) incl += y;
  }
  if (t < nb) bsum[t] = incl - x;
}

__global__ void k_scanC(int* __restrict__ rp, const int* __restrict__ bsum, int n, int total) {
  int i = blockIdx.x * 256 + threadIdx.x;
  if (i < n) rp[i] += bsum[i >> 11];
  else if (i == n) rp[n] = total;
}

__global__ void k_fill(const int* __restrict__ src, const int* __restrict__ dst,
                       const int* __restrict__ rp, int* __restrict__ fill,
                       const float* __restrict__ dis,
                       int* __restrict__ csrc, float* __restrict__ ccoef, int E) {
  int i = blockIdx.x * 256 + threadIdx.x;
  if (i < E) {
    int d = dst[i], s = src[i];
    int pos = rp[d] + atomicAdd(&fill[d], 1);
    csrc[pos] = s;
    ccoef[pos] = dis[s] * dis[d];
  }
}

// ---------------- fp32 tiled GEMM: C[n][0..127] = A[n][0..K-1] @ W[K][128] ----------------
// block: 256 threads, 64 nodes; thread tile 8 nodes x 4 cols.

template <int K, bool BIAS, bool RELU>
__global__ __launch_bounds__(256) void k_gemm(const float* __restrict__ A,
                                              const float* __restrict__ W,
                                              const float* __restrict__ bias,
                                              float* __restrict__ C, int n) {
  __shared__ float a_t[32][64];    // [k][node]  8 KB
  __shared__ float w_t[32][128];   // [k][j]    16 KB
  int tid = threadIdx.x;
  int tx = tid & 31;   // j group: j = tx*4..tx*4+3
  int ty = tid >> 5;   // node group: nodes ty*8..ty*8+7
  int nb = blockIdx.x * 64;

  float4 acc[8];
#pragma unroll
  for (int i = 0; i < 8; ++i) acc[i] = make_float4(0.f, 0.f, 0.f, 0.f);

  for (int kc = 0; kc < K; kc += 32) {
    // stage A transposed: thread -> node = tid/4, kq = (tid%4)*8
    {
      int node = tid >> 2;
      int kq = (tid & 3) * 8;
      int row = nb + node;
      if (row >= n) row = n - 1;
      const float* ap = A + (size_t)row * K + kc + kq;
      float4 p0 = *(const float4*)ap;
      float4 p1 = *(const float4*)(ap + 4);
      a_t[kq + 0][node] = p0.x; a_t[kq + 1][node] = p0.y;
      a_t[kq + 2][node] = p0.z; a_t[kq + 3][node] = p0.w;
      a_t[kq + 4][node] = p1.x; a_t[kq + 5][node] = p1.y;
      a_t[kq + 6][node] = p1.z; a_t[kq + 7][node] = p1.w;
    }
    // stage W: 32 rows x 128 cols
    {
      int col = (tid & 31) * 4;
      int r0 = tid >> 5;
#pragma unroll
      for (int i = 0; i < 4; ++i) {
        int row = r0 + i * 8;
        *(float4*)&w_t[row][col] = *(const float4*)&W[(size_t)(kc + row) * 128 + col];
      }
    }
    __syncthreads();
#pragma unroll 8
    for (int kk = 0; kk < 32; ++kk) {
      float4 a0 = *(const float4*)&a_t[kk][ty * 8];
      float4 a1 = *(const float4*)&a_t[kk][ty * 8 + 4];
      float4 wv = *(const float4*)&w_t[kk][tx * 4];
      fma4(acc[0], a0.x, wv); fma4(acc[1], a0.y, wv);
      fma4(acc[2], a0.z, wv); fma4(acc[3], a0.w, wv);
      fma4(acc[4], a1.x, wv); fma4(acc[5], a1.y, wv);
      fma4(acc[6], a1.z, wv); fma4(acc[7], a1.w, wv);
    }
    __syncthreads();
  }

  float4 bv = make_float4(0.f, 0.f, 0.f, 0.f);
  if constexpr (BIAS) bv = *(const float4*)&bias[tx * 4];
#pragma unroll
  for (int i = 0; i < 8; ++i) {
    int node = nb + ty * 8 + i;
    if (node < n) {
      float4 r = acc[i];
      if constexpr (BIAS) { r.x += bv.x; r.y += bv.y; r.z += bv.z; r.w += bv.w; }
      if constexpr (RELU) {
        r.x = fmaxf(r.x, 0.f); r.y = fmaxf(r.y, 0.f);
        r.z = fmaxf(r.z, 0.f); r.w = fmaxf(r.w, 0.f);
      }
      *(float4*)&C[(size_t)node * 128 + tx * 4] = r;
    }
  }
}

// ---------------- aggregation + bias + LayerNorm + ReLU ----------------
// one wave per node; lane owns channels 2*lane, 2*lane+1

__global__ __launch_bounds__(256) void k_agg(const float* __restrict__ hw,
                                             const int* __restrict__ rp,
                                             const int* __restrict__ csrc,
                                             const float* __restrict__ ccoef,
                                             const float* __restrict__ selfc,
                                             const float* __restrict__ bias,
                                             const float* __restrict__ g,
                                             const float* __restrict__ bln,
                                             float* __restrict__ out, int n) {
  int lane = threadIdx.x & 63;
  int node = blockIdx.x * 4 + (threadIdx.x >> 6);
  if (node >= n) return;
  int start = rp[node], end = rp[node + 1];
  const int c2 = lane * 2;
  float ax = 0.f, ay = 0.f;
  int e = start;
  for (; e + 2 <= end; e += 2) {
    int s0 = csrc[e], s1 = csrc[e + 1];
    float w0 = ccoef[e], w1 = ccoef[e + 1];
    float2 h0 = *(const float2*)&hw[(size_t)s0 * 128 + c2];
    float2 h1 = *(const float2*)&hw[(size_t)s1 * 128 + c2];
    ax = fmaf(w0, h0.x, ax); ay = fmaf(w0, h0.y, ay);
    ax = fmaf(w1, h1.x, ax); ay = fmaf(w1, h1.y, ay);
  }
  if (e < end) {
    int s0 = csrc[e];
    float w0 = ccoef[e];
    float2 h0 = *(const float2*)&hw[(size_t)s0 * 128 + c2];
    ax = fmaf(w0, h0.x, ax); ay = fmaf(w0, h0.y, ay);
  }
  // self loop + bias
  float sc = selfc[node];
  float2 hs = *(const float2*)&hw[(size_t)node * 128 + c2];
  ax = fmaf(sc, hs.x, ax); ay = fmaf(sc, hs.y, ay);
  float2 bb = *(const float2*)&bias[c2];
  ax += bb.x; ay += bb.y;
  // LayerNorm over 128 channels (wave reduction)
  float s1v = ax + ay;
  float s2v = ax * ax + ay * ay;
#pragma unroll
  for (int m = 1; m < 64; m <<= 1) {
    s1v += __shfl_xor(s1v, m, 64);
    s2v += __shfl_xor(s2v, m, 64);
  }
  float mean = s1v * (1.0f / 128.0f);
  float var = s2v * (1.0f / 128.0f) - mean * mean;
  float rstd = rsqrtf(var + LN_EPS);
  float2 gg = *(const float2*)&g[c2];
  float2 bl = *(const float2*)&bln[c2];
  float y0 = fmaxf(fmaf((ax - mean) * rstd, gg.x, bl.x), 0.f);
  float y1 = fmaxf(fmaf((ay - mean) * rstd, gg.y, bl.y), 0.f);
  *(float2*)&out[(size_t)node * 128 + c2] = make_float2(y0, y1);
}

// ---------------- output head: out[n][16] = concat(x1,x2)[n][256] @ ow[256][16] + ob ----------------

__global__ __launch_bounds__(256) void k_out(const float* __restrict__ x1,
                                             const float* __restrict__ x2,
                                             const float* __restrict__ w,
                                             const float* __restrict__ b,
                                             float* __restrict__ out, int n) {
  __shared__ float wl[256 * 16];
  __shared__ float bl[16];
  int tid = threadIdx.x;
#pragma unroll
  for (int i = 0; i < 4; ++i) {
    int idx = (i * 256 + tid) * 4;
    *(float4*)&wl[idx] = *(const float4*)&w[idx];
  }
  if (tid < 16) bl[tid] = b[tid];
  __syncthreads();
  int node = blockIdx.x * 256 + tid;
  if (node >= n) return;
  float acc[16];
#pragma unroll
  for (int o = 0; o < 16; ++o) acc[o] = bl[o];
  const float* xr = x1 + (size_t)node * 128;
#pragma unroll 4
  for (int c = 0; c < 128; c += 4) {
    float4 xv = *(const float4*)&xr[c];
#pragma unroll
    for (int o = 0; o < 16; ++o) {
      acc[o] = fmaf(xv.x, wl[(c + 0) * 16 + o],
               fmaf(xv.y, wl[(c + 1) * 16 + o],
               fmaf(xv.z, wl[(c + 2) * 16 + o],
               fmaf(xv.w, wl[(c + 3) * 16 + o], acc[o]))));
    }
  }
  const float* xr2 = x2 + (size_t)node * 128;
#pragma unroll 4
  for (int c = 0; c < 128; c += 4) {
    float4 xv = *(const float4*)&xr2[c];
#pragma unroll
    for (int o = 0; o < 16; ++o) {
      acc[o] = fmaf(xv.x, wl[(128 + c + 0) * 16 + o],
               fmaf(xv.y, wl[(128 + c + 1) * 16 + o],
               fmaf(xv.z, wl[(128 + c + 2) * 16 + o],
               fmaf(xv.w, wl[(128 + c + 3) * 16 + o], acc[o]))));
    }
  }
#pragma unroll
  for (int o = 0; o < 4; ++o) {
    *(float4*)&out[(size_t)node * 16 + o * 4] =
        make_float4(acc[o * 4], acc[o * 4 + 1], acc[o * 4 + 2], acc[o * 4 + 3]);
  }
}

// ---------------- host ----------------

extern "C" void kernel_launch(void* const* d_in, const int* in_sizes, int n_in,
                              void* d_out, int out_size, void* d_ws, size_t ws_size,
                              hipStream_t stream) {
  const float* x = (const float*)d_in[0];
  const int* ei1 = (const int*)d_in[1];
  const int* ei2 = (const int*)d_in[2];
  const float* enc_w = (const float*)d_in[3];
  const float* enc_b = (const float*)d_in[4];
  const float* conv_w[3] = {(const float*)d_in[5], (const float*)d_in[9], (const float*)d_in[13]};
  const float* conv_b[3] = {(const float*)d_in[6], (const float*)d_in[10], (const float*)d_in[14]};
  const float* ln_g[3] = {(const float*)d_in[7], (const float*)d_in[11], (const float*)d_in[15]};
  const float* ln_b[3] = {(const float*)d_in[8], (const float*)d_in[12], (const float*)d_in[16]};
  const float* out_w = (const float*)d_in[17];
  const float* out_b = (const float*)d_in[18];
  float* out = (float*)d_out;

  const int N = NN;
  const int E = in_sizes[1] / 2;

  char* ws = (char*)d_ws;
  size_t off = 0;
  auto alloc = [&](size_t bytes) -> char* {
    char* p = ws + off;
    off += (bytes + 255) & ~(size_t)255;
    return p;
  };
  float* buf0 = (float*)alloc((size_t)N * 128 * 4);
  float* buf1 = (float*)alloc((size_t)N * 128 * 4);
  float* buf2 = (float*)alloc((size_t)N * 128 * 4);

  struct G {
    int* deg; int* fill; float* dis; float* selfc; int* rp; int* bsum;
    int* csrc; float* ccoef; const int* src; const int* dst;
  } g[2];
  for (int i = 0; i < 2; ++i) {
    g[i].deg = (int*)alloc((size_t)N * 4);
    g[i].fill = (int*)alloc((size_t)N * 4);
    g[i].dis = (float*)alloc((size_t)N * 4);
    g[i].selfc = (float*)alloc((size_t)N * 4);
    g[i].rp = (int*)alloc((size_t)(N + 1) * 4);
    g[i].bsum = (int*)alloc(64 * 4);
    g[i].csrc = (int*)alloc((size_t)E * 4);
    g[i].ccoef = (float*)alloc((size_t)E * 4);
  }
  g[0].src = ei1; g[0].dst = ei1 + E;
  g[1].src = ei2; g[1].dst = ei2 + E;

  int nbScan = (N + 2047) / 2048;
  for (int i = 0; i < 2; ++i) {
    hipMemsetAsync(g[i].deg, 0, (size_t)N * 4, stream);
    hipMemsetAsync(g[i].fill, 0, (size_t)N * 4, stream);
    k_hist<<<(E + 255) / 256, 256, 0, stream>>>(g[i].dst, g[i].deg, E);
    k_dis<<<(N + 255) / 256, 256, 0, stream>>>(g[i].deg, g[i].dis, g[i].selfc, N);
    k_scanA<<<nbScan, 256, 0, stream>>>(g[i].deg, g[i].rp, g[i].bsum, N);
    k_scanB<<<1, 64, 0, stream>>>(g[i].bsum, nbScan);
    k_scanC<<<(N + 1 + 255) / 256, 256, 0, stream>>>(g[i].rp, g[i].bsum, N, E);
    k_fill<<<(E + 255) / 256, 256, 0, stream>>>(g[i].src, g[i].dst, g[i].rp, g[i].fill,
                                                g[i].dis, g[i].csrc, g[i].ccoef, E);
  }

  int gb = (N + 63) / 64;
  // shared encoder
  k_gemm<64, true, true><<<gb, 256, 0, stream>>>(x, enc_w, enc_b, buf0, N);

  // branch 1: buf0 (h0, preserved) -> ... -> x1 in buf2
  {
    const float* cur = buf0;
    for (int l = 0; l < 3; ++l) {
      k_gemm<128, false, false><<<gb, 256, 0, stream>>>(cur, conv_w[l], nullptr, buf1, N);
      k_agg<<<(N + 3) / 4, 256, 0, stream>>>(buf1, g[0].rp, g[0].csrc, g[0].ccoef,
                                             g[0].selfc, conv_b[l], ln_g[l], ln_b[l], buf2, N);
      cur = buf2;
    }
  }
  // branch 2: reuse buf0 as ping (h0 consumed by first gemm) -> x2 in buf0
  {
    const float* cur = buf0;
    for (int l = 0; l < 3; ++l) {
      k_gemm<128, false, false><<<gb, 256, 0, stream>>>(cur, conv_w[l], nullptr, buf1, N);
      k_agg<<<(N + 3) / 4, 256, 0, stream>>>(buf1, g[1].rp, g[1].csrc, g[1].ccoef,
                                             g[1].selfc, conv_b[l], ln_g[l], ln_b[l], buf0, N);
      cur = buf0;
    }
  }

  k_out<<<(N + 255) / 256, 256, 0, stream>>>(buf2, buf0, out_w, out_b, out, N);
}

// Round 2
// 1160.018 us; speedup vs baseline: 1.2094x; 1.2094x over previous
//
#include <hip/hip_runtime.h>

#define NN 100000
#define LN_EPS 1e-5f

typedef unsigned int uint_t;
typedef unsigned short ushort_t;

__device__ __forceinline__ void fma4(float4& a, float s, const float4& w) {
  a.x = fmaf(s, w.x, a.x);
  a.y = fmaf(s, w.y, a.y);
  a.z = fmaf(s, w.z, a.z);
  a.w = fmaf(s, w.w, a.w);
}

// round-to-nearest-even f32 -> bf16 (as uint bits in high/low half)
__device__ __forceinline__ uint_t pack_bf16x2(float a, float b) {
  uint_t ua = __float_as_uint(a);
  ua = (ua + 0x7FFFu + ((ua >> 16) & 1u)) >> 16;
  uint_t ub = __float_as_uint(b);
  ub = (ub + 0x7FFFu + ((ub >> 16) & 1u)) & 0xFFFF0000u;
  return ua | ub;
}

// ---------------- CSR build ----------------

__global__ void k_hist(const int* __restrict__ dst, int* __restrict__ deg, int E) {
  int i = blockIdx.x * 256 + threadIdx.x;
  if (i < E) atomicAdd(&deg[dst[i]], 1);
}

__global__ void k_dis(const int* __restrict__ deg, float* __restrict__ dis,
                      float* __restrict__ selfc, int n) {
  int i = blockIdx.x * 256 + threadIdx.x;
  if (i < n) {
    float d = (float)(deg[i] + 1);   // +1 self loop
    dis[i] = rsqrtf(d);
    selfc[i] = 1.0f / d;
  }
}

// block scans 2048 elements (8 per thread); writes local-exclusive scan + block sums
__global__ void k_scanA(const int* __restrict__ deg, int* __restrict__ rp,
                        int* __restrict__ bsum, int n) {
  __shared__ int sh[256];
  int t = threadIdx.x;
  int base = blockIdx.x * 2048 + t * 8;
  int v[8];
  int s = 0;
#pragma unroll
  for (int i = 0; i < 8; ++i) {
    int idx = base + i;
    v[i] = (idx < n) ? deg[idx] : 0;
    s += v[i];
  }
  sh[t] = s;
  __syncthreads();
  for (int d = 1; d < 256; d <<= 1) {
    int add = (t >= d) ? sh[t - d] : 0;
    __syncthreads();
    sh[t] += add;
    __syncthreads();
  }
  int excl = sh[t] - s;
  if (t == 255) bsum[blockIdx.x] = sh[255];
  int run = excl;
#pragma unroll
  for (int i = 0; i < 8; ++i) {
    int idx = base + i;
    if (idx < n) rp[idx] = run;
    run += v[i];
  }
}

// single wave scans the (<=64) block sums in place (exclusive)
__global__ void k_scanB(int* bsum, int nb) {
  int t = threadIdx.x;
  int x = (t < nb) ? bsum[t] : 0;
  int incl = x;
#pragma unroll
  for (int d = 1; d < 64; d <<= 1) {
    int y = __shfl_up(incl, d, 64);
    if (t >= d) incl += y;
  }
  if (t < nb) bsum[t] = incl - x;
}

__global__ void k_scanC(int* __restrict__ rp, const int* __restrict__ bsum, int n, int total) {
  int i = blockIdx.x * 256 + threadIdx.x;
  if (i < n) rp[i] += bsum[i >> 11];
  else if (i == n) rp[n] = total;
}

__global__ void k_fill(const int* __restrict__ src, const int* __restrict__ dst,
                       const int* __restrict__ rp, int* __restrict__ fill,
                       const float* __restrict__ dis,
                       int* __restrict__ csrc, float* __restrict__ ccoef, int E) {
  int i = blockIdx.x * 256 + threadIdx.x;
  if (i < E) {
    int d = dst[i], s = src[i];
    int pos = rp[d] + atomicAdd(&fill[d], 1);
    csrc[pos] = s;
    ccoef[pos] = dis[s] * dis[d];
  }
}

// ---------------- fp32 tiled GEMM: C[n][0..127] = A[n][0..K-1] @ W[K][128] ----------------
// block: 256 threads, 64 nodes; thread tile 8 nodes x 4 cols.
// BF16OUT: write bf16 (for the aggregation gather buffer)

template <int K, bool BIAS, bool RELU, bool BF16OUT>
__global__ __launch_bounds__(256) void k_gemm(const float* __restrict__ A,
                                              const float* __restrict__ W,
                                              const float* __restrict__ bias,
                                              void* __restrict__ Cv, int n) {
  __shared__ float a_t[32][64];    // [k][node]  8 KB
  __shared__ float w_t[32][128];   // [k][j]    16 KB
  int tid = threadIdx.x;
  int tx = tid & 31;   // j group: j = tx*4..tx*4+3
  int ty = tid >> 5;   // node group: nodes ty*8..ty*8+7
  int nb = blockIdx.x * 64;

  float4 acc[8];
#pragma unroll
  for (int i = 0; i < 8; ++i) acc[i] = make_float4(0.f, 0.f, 0.f, 0.f);

  for (int kc = 0; kc < K; kc += 32) {
    // stage A transposed: thread -> node = tid/4, kq = (tid%4)*8
    {
      int node = tid >> 2;
      int kq = (tid & 3) * 8;
      int row = nb + node;
      if (row >= n) row = n - 1;
      const float* ap = A + (size_t)row * K + kc + kq;
      float4 p0 = *(const float4*)ap;
      float4 p1 = *(const float4*)(ap + 4);
      a_t[kq + 0][node] = p0.x; a_t[kq + 1][node] = p0.y;
      a_t[kq + 2][node] = p0.z; a_t[kq + 3][node] = p0.w;
      a_t[kq + 4][node] = p1.x; a_t[kq + 5][node] = p1.y;
      a_t[kq + 6][node] = p1.z; a_t[kq + 7][node] = p1.w;
    }
    // stage W: 32 rows x 128 cols
    {
      int col = (tid & 31) * 4;
      int r0 = tid >> 5;
#pragma unroll
      for (int i = 0; i < 4; ++i) {
        int row = r0 + i * 8;
        *(float4*)&w_t[row][col] = *(const float4*)&W[(size_t)(kc + row) * 128 + col];
      }
    }
    __syncthreads();
#pragma unroll 8
    for (int kk = 0; kk < 32; ++kk) {
      float4 a0 = *(const float4*)&a_t[kk][ty * 8];
      float4 a1 = *(const float4*)&a_t[kk][ty * 8 + 4];
      float4 wv = *(const float4*)&w_t[kk][tx * 4];
      fma4(acc[0], a0.x, wv); fma4(acc[1], a0.y, wv);
      fma4(acc[2], a0.z, wv); fma4(acc[3], a0.w, wv);
      fma4(acc[4], a1.x, wv); fma4(acc[5], a1.y, wv);
      fma4(acc[6], a1.z, wv); fma4(acc[7], a1.w, wv);
    }
    __syncthreads();
  }

  float4 bv = make_float4(0.f, 0.f, 0.f, 0.f);
  if constexpr (BIAS) bv = *(const float4*)&bias[tx * 4];
#pragma unroll
  for (int i = 0; i < 8; ++i) {
    int node = nb + ty * 8 + i;
    if (node < n) {
      float4 r = acc[i];
      if constexpr (BIAS) { r.x += bv.x; r.y += bv.y; r.z += bv.z; r.w += bv.w; }
      if constexpr (RELU) {
        r.x = fmaxf(r.x, 0.f); r.y = fmaxf(r.y, 0.f);
        r.z = fmaxf(r.z, 0.f); r.w = fmaxf(r.w, 0.f);
      }
      if constexpr (BF16OUT) {
        ushort_t* C = (ushort_t*)Cv;
        uint2 p;
        p.x = pack_bf16x2(r.x, r.y);
        p.y = pack_bf16x2(r.z, r.w);
        *(uint2*)&C[(size_t)node * 128 + tx * 4] = p;
      } else {
        float* C = (float*)Cv;
        *(float4*)&C[(size_t)node * 128 + tx * 4] = r;
      }
    }
  }
}

// ---------------- aggregation + bias + LayerNorm + ReLU ----------------
// one wave per node; lane owns channels 2*lane, 2*lane+1. hw is bf16.

__device__ __forceinline__ float bf_lo(uint_t u) { return __uint_as_float(u << 16); }
__device__ __forceinline__ float bf_hi(uint_t u) { return __uint_as_float(u & 0xFFFF0000u); }

__global__ __launch_bounds__(256) void k_agg(const ushort_t* __restrict__ hw,
                                             const int* __restrict__ rp,
                                             const int* __restrict__ csrc,
                                             const float* __restrict__ ccoef,
                                             const float* __restrict__ selfc,
                                             const float* __restrict__ bias,
                                             const float* __restrict__ g,
                                             const float* __restrict__ bln,
                                             float* __restrict__ out, int n) {
  int lane = threadIdx.x & 63;
  int node = blockIdx.x * 4 + (threadIdx.x >> 6);
  if (node >= n) return;
  int start = rp[node], end = rp[node + 1];
  const int c2 = lane * 2;
  float ax = 0.f, ay = 0.f;
  int e = start;
  for (; e + 4 <= end; e += 4) {
    int s0 = csrc[e], s1 = csrc[e + 1], s2 = csrc[e + 2], s3 = csrc[e + 3];
    float w0 = ccoef[e], w1 = ccoef[e + 1], w2 = ccoef[e + 2], w3 = ccoef[e + 3];
    uint_t u0 = *(const uint_t*)&hw[(size_t)s0 * 128 + c2];
    uint_t u1 = *(const uint_t*)&hw[(size_t)s1 * 128 + c2];
    uint_t u2 = *(const uint_t*)&hw[(size_t)s2 * 128 + c2];
    uint_t u3 = *(const uint_t*)&hw[(size_t)s3 * 128 + c2];
    ax = fmaf(w0, bf_lo(u0), ax); ay = fmaf(w0, bf_hi(u0), ay);
    ax = fmaf(w1, bf_lo(u1), ax); ay = fmaf(w1, bf_hi(u1), ay);
    ax = fmaf(w2, bf_lo(u2), ax); ay = fmaf(w2, bf_hi(u2), ay);
    ax = fmaf(w3, bf_lo(u3), ax); ay = fmaf(w3, bf_hi(u3), ay);
  }
  for (; e < end; ++e) {
    int s0 = csrc[e];
    float w0 = ccoef[e];
    uint_t u0 = *(const uint_t*)&hw[(size_t)s0 * 128 + c2];
    ax = fmaf(w0, bf_lo(u0), ax); ay = fmaf(w0, bf_hi(u0), ay);
  }
  // self loop + bias
  float sc = selfc[node];
  uint_t us = *(const uint_t*)&hw[(size_t)node * 128 + c2];
  ax = fmaf(sc, bf_lo(us), ax); ay = fmaf(sc, bf_hi(us), ay);
  float2 bb = *(const float2*)&bias[c2];
  ax += bb.x; ay += bb.y;
  // LayerNorm over 128 channels (wave reduction)
  float s1v = ax + ay;
  float s2v = ax * ax + ay * ay;
#pragma unroll
  for (int m = 1; m < 64; m <<= 1) {
    s1v += __shfl_xor(s1v, m, 64);
    s2v += __shfl_xor(s2v, m, 64);
  }
  float mean = s1v * (1.0f / 128.0f);
  float var = s2v * (1.0f / 128.0f) - mean * mean;
  float rstd = rsqrtf(var + LN_EPS);
  float2 gg = *(const float2*)&g[c2];
  float2 bl = *(const float2*)&bln[c2];
  float y0 = fmaxf(fmaf((ax - mean) * rstd, gg.x, bl.x), 0.f);
  float y1 = fmaxf(fmaf((ay - mean) * rstd, gg.y, bl.y), 0.f);
  *(float2*)&out[(size_t)node * 128 + c2] = make_float2(y0, y1);
}

// ---------------- output head: out[n][16] = concat(x1,x2)[n][256] @ ow[256][16] + ob ----------------

__global__ __launch_bounds__(256) void k_out(const float* __restrict__ x1,
                                             const float* __restrict__ x2,
                                             const float* __restrict__ w,
                                             const float* __restrict__ b,
                                             float* __restrict__ out, int n) {
  __shared__ float wl[256 * 16];
  __shared__ float bl[16];
  int tid = threadIdx.x;
#pragma unroll
  for (int i = 0; i < 4; ++i) {
    int idx = (i * 256 + tid) * 4;
    *(float4*)&wl[idx] = *(const float4*)&w[idx];
  }
  if (tid < 16) bl[tid] = b[tid];
  __syncthreads();
  int node = blockIdx.x * 256 + tid;
  if (node >= n) return;
  float acc[16];
#pragma unroll
  for (int o = 0; o < 16; ++o) acc[o] = bl[o];
  const float* xr = x1 + (size_t)node * 128;
#pragma unroll 4
  for (int c = 0; c < 128; c += 4) {
    float4 xv = *(const float4*)&xr[c];
#pragma unroll
    for (int o = 0; o < 16; ++o) {
      acc[o] = fmaf(xv.x, wl[(c + 0) * 16 + o],
               fmaf(xv.y, wl[(c + 1) * 16 + o],
               fmaf(xv.z, wl[(c + 2) * 16 + o],
               fmaf(xv.w, wl[(c + 3) * 16 + o], acc[o]))));
    }
  }
  const float* xr2 = x2 + (size_t)node * 128;
#pragma unroll 4
  for (int c = 0; c < 128; c += 4) {
    float4 xv = *(const float4*)&xr2[c];
#pragma unroll
    for (int o = 0; o < 16; ++o) {
      acc[o] = fmaf(xv.x, wl[(128 + c + 0) * 16 + o],
               fmaf(xv.y, wl[(128 + c + 1) * 16 + o],
               fmaf(xv.z, wl[(128 + c + 2) * 16 + o],
               fmaf(xv.w, wl[(128 + c + 3) * 16 + o], acc[o]))));
    }
  }
#pragma unroll
  for (int o = 0; o < 4; ++o) {
    *(float4*)&out[(size_t)node * 16 + o * 4] =
        make_float4(acc[o * 4], acc[o * 4 + 1], acc[o * 4 + 2], acc[o * 4 + 3]);
  }
}

// ---------------- host ----------------

extern "C" void kernel_launch(void* const* d_in, const int* in_sizes, int n_in,
                              void* d_out, int out_size, void* d_ws, size_t ws_size,
                              hipStream_t stream) {
  const float* x = (const float*)d_in[0];
  const int* ei1 = (const int*)d_in[1];
  const int* ei2 = (const int*)d_in[2];
  const float* enc_w = (const float*)d_in[3];
  const float* enc_b = (const float*)d_in[4];
  const float* conv_w[3] = {(const float*)d_in[5], (const float*)d_in[9], (const float*)d_in[13]};
  const float* conv_b[3] = {(const float*)d_in[6], (const float*)d_in[10], (const float*)d_in[14]};
  const float* ln_g[3] = {(const float*)d_in[7], (const float*)d_in[11], (const float*)d_in[15]};
  const float* ln_b[3] = {(const float*)d_in[8], (const float*)d_in[12], (const float*)d_in[16]};
  const float* out_w = (const float*)d_in[17];
  const float* out_b = (const float*)d_in[18];
  float* out = (float*)d_out;

  const int N = NN;
  const int E = in_sizes[1] / 2;

  char* ws = (char*)d_ws;
  size_t off = 0;
  auto alloc = [&](size_t bytes) -> char* {
    char* p = ws + off;
    off += (bytes + 255) & ~(size_t)255;
    return p;
  };
  float* buf0 = (float*)alloc((size_t)N * 128 * 4);   // fp32 ping (GEMM A input / agg out)
  float* buf2 = (float*)alloc((size_t)N * 128 * 4);   // fp32 pong
  ushort_t* hbuf = (ushort_t*)alloc((size_t)N * 128 * 2);  // bf16 gather buffer

  struct G {
    int* deg; int* fill; float* dis; float* selfc; int* rp; int* bsum;
    int* csrc; float* ccoef; const int* src; const int* dst;
  } g[2];
  for (int i = 0; i < 2; ++i) {
    g[i].deg = (int*)alloc((size_t)N * 4);
    g[i].fill = (int*)alloc((size_t)N * 4);
    g[i].dis = (float*)alloc((size_t)N * 4);
    g[i].selfc = (float*)alloc((size_t)N * 4);
    g[i].rp = (int*)alloc((size_t)(N + 1) * 4);
    g[i].bsum = (int*)alloc(64 * 4);
    g[i].csrc = (int*)alloc((size_t)E * 4);
    g[i].ccoef = (float*)alloc((size_t)E * 4);
  }
  g[0].src = ei1; g[0].dst = ei1 + E;
  g[1].src = ei2; g[1].dst = ei2 + E;

  int nbScan = (N + 2047) / 2048;
  for (int i = 0; i < 2; ++i) {
    hipMemsetAsync(g[i].deg, 0, (size_t)N * 4, stream);
    hipMemsetAsync(g[i].fill, 0, (size_t)N * 4, stream);
    k_hist<<<(E + 255) / 256, 256, 0, stream>>>(g[i].dst, g[i].deg, E);
    k_dis<<<(N + 255) / 256, 256, 0, stream>>>(g[i].deg, g[i].dis, g[i].selfc, N);
    k_scanA<<<nbScan, 256, 0, stream>>>(g[i].deg, g[i].rp, g[i].bsum, N);
    k_scanB<<<1, 64, 0, stream>>>(g[i].bsum, nbScan);
    k_scanC<<<(N + 1 + 255) / 256, 256, 0, stream>>>(g[i].rp, g[i].bsum, N, E);
    k_fill<<<(E + 255) / 256, 256, 0, stream>>>(g[i].src, g[i].dst, g[i].rp, g[i].fill,
                                                g[i].dis, g[i].csrc, g[i].ccoef, E);
  }

  int gb = (N + 63) / 64;
  // shared encoder -> buf0 (fp32, preserved as h0 for both branches)
  k_gemm<64, true, true, false><<<gb, 256, 0, stream>>>(x, enc_w, enc_b, buf0, N);

  // branch 1: buf0 (h0) -> ... -> x1 in buf2
  {
    const float* cur = buf0;
    for (int l = 0; l < 3; ++l) {
      k_gemm<128, false, false, true><<<gb, 256, 0, stream>>>(cur, conv_w[l], nullptr, hbuf, N);
      k_agg<<<(N + 3) / 4, 256, 0, stream>>>(hbuf, g[0].rp, g[0].csrc, g[0].ccoef,
                                             g[0].selfc, conv_b[l], ln_g[l], ln_b[l], buf2, N);
      cur = buf2;
    }
  }
  // branch 2: buf0 (h0) consumed by first gemm, then reused as ping -> x2 in buf0
  {
    const float* cur = buf0;
    for (int l = 0; l < 3; ++l) {
      k_gemm<128, false, false, true><<<gb, 256, 0, stream>>>(cur, conv_w[l], nullptr, hbuf, N);
      k_agg<<<(N + 3) / 4, 256, 0, stream>>>(hbuf, g[1].rp, g[1].csrc, g[1].ccoef,
                                             g[1].selfc, conv_b[l], ln_g[l], ln_b[l], buf0, N);
      cur = buf0;
    }
  }

  k_out<<<(N + 255) / 256, 256, 0, stream>>>(buf2, buf0, out_w, out_b, out, N);
}

// Round 3
// 974.515 us; speedup vs baseline: 1.4396x; 1.1904x over previous
//
#include <hip/hip_runtime.h>

#define NN 100000
#define LN_EPS 1e-5f

typedef unsigned int uint_t;
typedef unsigned short ushort_t;
typedef __attribute__((ext_vector_type(8))) short short8v;
typedef __attribute__((ext_vector_type(4))) float f32x4;

__device__ __forceinline__ void fma4(float4& a, float s, const float4& w) {
  a.x = fmaf(s, w.x, a.x);
  a.y = fmaf(s, w.y, a.y);
  a.z = fmaf(s, w.z, a.z);
  a.w = fmaf(s, w.w, a.w);
}

// round-to-nearest-even f32 -> bf16
__device__ __forceinline__ ushort_t bf16_rte(float x) {
  uint_t u = __float_as_uint(x);
  u = (u + 0x7FFFu + ((u >> 16) & 1u)) >> 16;
  return (ushort_t)u;
}
__device__ __forceinline__ uint_t pack_bf16x2(float a, float b) {
  uint_t ua = __float_as_uint(a);
  ua = (ua + 0x7FFFu + ((ua >> 16) & 1u)) >> 16;
  uint_t ub = __float_as_uint(b);
  ub = (ub + 0x7FFFu + ((ub >> 16) & 1u)) & 0xFFFF0000u;
  return ua | ub;
}
__device__ __forceinline__ float bf_lo(uint_t u) { return __uint_as_float(u << 16); }
__device__ __forceinline__ float bf_hi(uint_t u) { return __uint_as_float(u & 0xFFFF0000u); }

// ---------------- CSR build ----------------

__global__ void k_hist(const int* __restrict__ dst, int* __restrict__ deg, int E) {
  int i = blockIdx.x * 256 + threadIdx.x;
  if (i < E) atomicAdd(&deg[dst[i]], 1);
}

__global__ void k_dis(const int* __restrict__ deg, float* __restrict__ dis, int n) {
  int i = blockIdx.x * 256 + threadIdx.x;
  if (i < n) dis[i] = rsqrtf((float)(deg[i] + 1));   // +1 self loop
}

// block scans 2048 elements (8 per thread)
__global__ void k_scanA(const int* __restrict__ deg, int* __restrict__ rp,
                        int* __restrict__ bsum, int n) {
  __shared__ int sh[256];
  int t = threadIdx.x;
  int base = blockIdx.x * 2048 + t * 8;
  int v[8];
  int s = 0;
#pragma unroll
  for (int i = 0; i < 8; ++i) {
    int idx = base + i;
    v[i] = (idx < n) ? deg[idx] : 0;
    s += v[i];
  }
  sh[t] = s;
  __syncthreads();
  for (int d = 1; d < 256; d <<= 1) {
    int add = (t >= d) ? sh[t - d] : 0;
    __syncthreads();
    sh[t] += add;
    __syncthreads();
  }
  int excl = sh[t] - s;
  if (t == 255) bsum[blockIdx.x] = sh[255];
  int run = excl;
#pragma unroll
  for (int i = 0; i < 8; ++i) {
    int idx = base + i;
    if (idx < n) rp[idx] = run;
    run += v[i];
  }
}

__global__ void k_scanB(int* bsum, int nb) {
  int t = threadIdx.x;
  int x = (t < nb) ? bsum[t] : 0;
  int incl = x;
#pragma unroll
  for (int d = 1; d < 64; d <<= 1) {
    int y = __shfl_up(incl, d, 64);
    if (t >= d) incl += y;
  }
  if (t < nb) bsum[t] = incl - x;
}

__global__ void k_scanC(int* __restrict__ rp, const int* __restrict__ bsum, int n, int total) {
  int i = blockIdx.x * 256 + threadIdx.x;
  if (i < n) rp[i] += bsum[i >> 11];
  else if (i == n) rp[n] = total;
}

// only csrc is scattered now (1 random 4B write per edge)
__global__ void k_fill(const int* __restrict__ src, const int* __restrict__ dst,
                       const int* __restrict__ rp, int* __restrict__ fill,
                       int* __restrict__ csrc, int E) {
  int i = blockIdx.x * 256 + threadIdx.x;
  if (i < E) {
    int d = dst[i];
    int pos = rp[d] + atomicAdd(&fill[d], 1);
    csrc[pos] = src[i];
  }
}

// ---------------- fp32 tiled GEMM (encoder only): bf16 out ----------------

template <int K>
__global__ __launch_bounds__(256) void k_gemm_enc(const float* __restrict__ A,
                                                  const float* __restrict__ W,
                                                  const float* __restrict__ bias,
                                                  ushort_t* __restrict__ C, int n) {
  __shared__ float a_t[32][64];
  __shared__ float w_t[32][128];
  int tid = threadIdx.x;
  int tx = tid & 31;
  int ty = tid >> 5;
  int nb = blockIdx.x * 64;

  float4 acc[8];
#pragma unroll
  for (int i = 0; i < 8; ++i) acc[i] = make_float4(0.f, 0.f, 0.f, 0.f);

  for (int kc = 0; kc < K; kc += 32) {
    {
      int node = tid >> 2;
      int kq = (tid & 3) * 8;
      int row = nb + node;
      if (row >= n) row = n - 1;
      const float* ap = A + (size_t)row * K + kc + kq;
      float4 p0 = *(const float4*)ap;
      float4 p1 = *(const float4*)(ap + 4);
      a_t[kq + 0][node] = p0.x; a_t[kq + 1][node] = p0.y;
      a_t[kq + 2][node] = p0.z; a_t[kq + 3][node] = p0.w;
      a_t[kq + 4][node] = p1.x; a_t[kq + 5][node] = p1.y;
      a_t[kq + 6][node] = p1.z; a_t[kq + 7][node] = p1.w;
    }
    {
      int col = (tid & 31) * 4;
      int r0 = tid >> 5;
#pragma unroll
      for (int i = 0; i < 4; ++i) {
        int row = r0 + i * 8;
        *(float4*)&w_t[row][col] = *(const float4*)&W[(size_t)(kc + row) * 128 + col];
      }
    }
    __syncthreads();
#pragma unroll 8
    for (int kk = 0; kk < 32; ++kk) {
      float4 a0 = *(const float4*)&a_t[kk][ty * 8];
      float4 a1 = *(const float4*)&a_t[kk][ty * 8 + 4];
      float4 wv = *(const float4*)&w_t[kk][tx * 4];
      fma4(acc[0], a0.x, wv); fma4(acc[1], a0.y, wv);
      fma4(acc[2], a0.z, wv); fma4(acc[3], a0.w, wv);
      fma4(acc[4], a1.x, wv); fma4(acc[5], a1.y, wv);
      fma4(acc[6], a1.z, wv); fma4(acc[7], a1.w, wv);
    }
    __syncthreads();
  }

  float4 bv = *(const float4*)&bias[tx * 4];
#pragma unroll
  for (int i = 0; i < 8; ++i) {
    int node = nb + ty * 8 + i;
    if (node < n) {
      float4 r = acc[i];
      r.x = fmaxf(r.x + bv.x, 0.f); r.y = fmaxf(r.y + bv.y, 0.f);
      r.z = fmaxf(r.z + bv.z, 0.f); r.w = fmaxf(r.w + bv.w, 0.f);
      uint2 p;
      p.x = pack_bf16x2(r.x, r.y);
      p.y = pack_bf16x2(r.z, r.w);
      *(uint2*)&C[(size_t)node * 128 + tx * 4] = p;
    }
  }
}

// ---------------- W pack: fp32 [128][128] -> bf16 MFMA B-frag order ----------------
// layout: [kk(4)][j(8)][lane(64)][8]; lane holds B[k=kk*32+(lane>>4)*8+i][col=j*16+(lane&15)]

__global__ void k_packw(const float* __restrict__ W, ushort_t* __restrict__ P) {
  int t = blockIdx.x * 256 + threadIdx.x;  // [0, 2048)
  int lane = t & 63;
  int j = (t >> 6) & 7;
  int kk = t >> 9;
  int krow = kk * 32 + (lane >> 4) * 8;
  int col = j * 16 + (lane & 15);
  ushort_t o[8];
#pragma unroll
  for (int i = 0; i < 8; ++i) o[i] = bf16_rte(W[(size_t)(krow + i) * 128 + col]);
  uint4 v;
  v.x = (uint_t)o[0] | ((uint_t)o[1] << 16);
  v.y = (uint_t)o[2] | ((uint_t)o[3] << 16);
  v.z = (uint_t)o[4] | ((uint_t)o[5] << 16);
  v.w = (uint_t)o[6] | ((uint_t)o[7] << 16);
  *(uint4*)&P[(size_t)t * 8] = v;
}

// ---------------- bf16 MFMA GEMM: C[row][col] = (A @ W) * dis[row], bf16 out ----------------
// one wave per 16 rows; LDS-free. A: [n][128] bf16 row-major.

__global__ __launch_bounds__(256) void k_gemm_mfma(const ushort_t* __restrict__ A,
                                                   const ushort_t* __restrict__ Wp,
                                                   const float* __restrict__ dis,
                                                   ushort_t* __restrict__ C, int n) {
  int lane = threadIdx.x & 63;
  int wid = threadIdx.x >> 6;
  int r0 = (blockIdx.x * 4 + wid) * 16;
  if (r0 >= n) return;
  int arow = r0 + (lane & 15);
  if (arow >= n) arow = n - 1;
  const ushort_t* aptr = A + (size_t)arow * 128 + (lane >> 4) * 8;

  f32x4 acc[8] = {};
#pragma unroll
  for (int kk = 0; kk < 4; ++kk) {
    short8v a = *(const short8v*)(aptr + kk * 32);
    const ushort_t* wp = Wp + ((size_t)(kk * 8) * 64 + lane) * 8;
#pragma unroll
    for (int j = 0; j < 8; ++j) {
      short8v b = *(const short8v*)(wp + (size_t)j * 512);
      acc[j] = __builtin_amdgcn_mfma_f32_16x16x32_bf16(a, b, acc[j], 0, 0, 0);
    }
  }
  // D: row = r0 + (lane>>4)*4 + reg, col = j*16 + (lane&15)
  int rbase = r0 + (lane >> 4) * 4;
  int colb = lane & 15;
#pragma unroll
  for (int reg = 0; reg < 4; ++reg) {
    int row = rbase + reg;
    if (row < n) {
      float s = dis[row];
#pragma unroll
      for (int j = 0; j < 8; ++j) {
        C[(size_t)row * 128 + j * 16 + colb] = bf16_rte(acc[j][reg] * s);
      }
    }
  }
}

// ---------------- aggregation + bias + LayerNorm + ReLU (bf16 in, bf16 out) ----------------
// hw rows are pre-scaled by dis[src]; agg = dis[node] * (sum_edges + self_row)

__global__ __launch_bounds__(256) void k_agg(const uint_t* __restrict__ hw,   // [n][64] bf16x2
                                             const int* __restrict__ rp,
                                             const int* __restrict__ csrc,
                                             const float* __restrict__ dis,
                                             const float* __restrict__ bias,
                                             const float* __restrict__ g,
                                             const float* __restrict__ bln,
                                             uint_t* __restrict__ out, int n) {
  int lane = threadIdx.x & 63;
  int node = blockIdx.x * 4 + (threadIdx.x >> 6);
  if (node >= n) return;
  int start = rp[node], end = rp[node + 1];
  float ax = 0.f, ay = 0.f;
  int e = start;
  for (; e + 4 <= end; e += 4) {
    int s0 = csrc[e], s1 = csrc[e + 1], s2 = csrc[e + 2], s3 = csrc[e + 3];
    uint_t u0 = hw[(size_t)s0 * 64 + lane];
    uint_t u1 = hw[(size_t)s1 * 64 + lane];
    uint_t u2 = hw[(size_t)s2 * 64 + lane];
    uint_t u3 = hw[(size_t)s3 * 64 + lane];
    ax += bf_lo(u0); ay += bf_hi(u0);
    ax += bf_lo(u1); ay += bf_hi(u1);
    ax += bf_lo(u2); ay += bf_hi(u2);
    ax += bf_lo(u3); ay += bf_hi(u3);
  }
  for (; e < end; ++e) {
    uint_t u0 = hw[(size_t)csrc[e] * 64 + lane];
    ax += bf_lo(u0); ay += bf_hi(u0);
  }
  // self loop (hw[node] is h[node]*dis[node]; total * dis[node] gives correct terms)
  uint_t us = hw[(size_t)node * 64 + lane];
  ax += bf_lo(us); ay += bf_hi(us);
  float dn = dis[node];
  const int c2 = lane * 2;
  float2 bb = *(const float2*)&bias[c2];
  ax = fmaf(ax, dn, bb.x);
  ay = fmaf(ay, dn, bb.y);
  // LayerNorm over 128 channels
  float s1v = ax + ay;
  float s2v = ax * ax + ay * ay;
#pragma unroll
  for (int m = 1; m < 64; m <<= 1) {
    s1v += __shfl_xor(s1v, m, 64);
    s2v += __shfl_xor(s2v, m, 64);
  }
  float mean = s1v * (1.0f / 128.0f);
  float var = s2v * (1.0f / 128.0f) - mean * mean;
  float rstd = rsqrtf(var + LN_EPS);
  float2 gg = *(const float2*)&g[c2];
  float2 bl = *(const float2*)&bln[c2];
  float y0 = fmaxf(fmaf((ax - mean) * rstd, gg.x, bl.x), 0.f);
  float y1 = fmaxf(fmaf((ay - mean) * rstd, gg.y, bl.y), 0.f);
  out[(size_t)node * 64 + lane] = pack_bf16x2(y0, y1);
}

// ---------------- output head: out[n][16] = concat(x1,x2)[n][256] @ ow[256][16] + ob ----------------

__global__ __launch_bounds__(256) void k_out(const ushort_t* __restrict__ x1,
                                             const ushort_t* __restrict__ x2,
                                             const float* __restrict__ w,
                                             const float* __restrict__ b,
                                             float* __restrict__ out, int n) {
  __shared__ float wl[256 * 16];
  __shared__ float bl[16];
  int tid = threadIdx.x;
#pragma unroll
  for (int i = 0; i < 4; ++i) {
    int idx = (i * 256 + tid) * 4;
    *(float4*)&wl[idx] = *(const float4*)&w[idx];
  }
  if (tid < 16) bl[tid] = b[tid];
  __syncthreads();
  int node = blockIdx.x * 256 + tid;
  if (node >= n) return;
  float acc[16];
#pragma unroll
  for (int o = 0; o < 16; ++o) acc[o] = bl[o];

  const ushort_t* xr = x1 + (size_t)node * 128;
#pragma unroll 2
  for (int c = 0; c < 128; c += 8) {
    uint4 xv = *(const uint4*)&xr[c];
    float f0 = bf_lo(xv.x), f1 = bf_hi(xv.x), f2 = bf_lo(xv.y), f3 = bf_hi(xv.y);
    float f4 = bf_lo(xv.z), f5 = bf_hi(xv.z), f6 = bf_lo(xv.w), f7 = bf_hi(xv.w);
#pragma unroll
    for (int o = 0; o < 16; ++o) {
      acc[o] = fmaf(f0, wl[(c + 0) * 16 + o],
               fmaf(f1, wl[(c + 1) * 16 + o],
               fmaf(f2, wl[(c + 2) * 16 + o],
               fmaf(f3, wl[(c + 3) * 16 + o],
               fmaf(f4, wl[(c + 4) * 16 + o],
               fmaf(f5, wl[(c + 5) * 16 + o],
               fmaf(f6, wl[(c + 6) * 16 + o],
               fmaf(f7, wl[(c + 7) * 16 + o], acc[o]))))))));
    }
  }
  const ushort_t* xr2 = x2 + (size_t)node * 128;
#pragma unroll 2
  for (int c = 0; c < 128; c += 8) {
    uint4 xv = *(const uint4*)&xr2[c];
    float f0 = bf_lo(xv.x), f1 = bf_hi(xv.x), f2 = bf_lo(xv.y), f3 = bf_hi(xv.y);
    float f4 = bf_lo(xv.z), f5 = bf_hi(xv.z), f6 = bf_lo(xv.w), f7 = bf_hi(xv.w);
#pragma unroll
    for (int o = 0; o < 16; ++o) {
      acc[o] = fmaf(f0, wl[(128 + c + 0) * 16 + o],
               fmaf(f1, wl[(128 + c + 1) * 16 + o],
               fmaf(f2, wl[(128 + c + 2) * 16 + o],
               fmaf(f3, wl[(128 + c + 3) * 16 + o],
               fmaf(f4, wl[(128 + c + 4) * 16 + o],
               fmaf(f5, wl[(128 + c + 5) * 16 + o],
               fmaf(f6, wl[(128 + c + 6) * 16 + o],
               fmaf(f7, wl[(128 + c + 7) * 16 + o], acc[o]))))))));
    }
  }
#pragma unroll
  for (int o = 0; o < 4; ++o) {
    *(float4*)&out[(size_t)node * 16 + o * 4] =
        make_float4(acc[o * 4], acc[o * 4 + 1], acc[o * 4 + 2], acc[o * 4 + 3]);
  }
}

// ---------------- host ----------------

extern "C" void kernel_launch(void* const* d_in, const int* in_sizes, int n_in,
                              void* d_out, int out_size, void* d_ws, size_t ws_size,
                              hipStream_t stream) {
  const float* x = (const float*)d_in[0];
  const int* ei1 = (const int*)d_in[1];
  const int* ei2 = (const int*)d_in[2];
  const float* enc_w = (const float*)d_in[3];
  const float* enc_b = (const float*)d_in[4];
  const float* conv_w[3] = {(const float*)d_in[5], (const float*)d_in[9], (const float*)d_in[13]};
  const float* conv_b[3] = {(const float*)d_in[6], (const float*)d_in[10], (const float*)d_in[14]};
  const float* ln_g[3] = {(const float*)d_in[7], (const float*)d_in[11], (const float*)d_in[15]};
  const float* ln_b[3] = {(const float*)d_in[8], (const float*)d_in[12], (const float*)d_in[16]};
  const float* out_w = (const float*)d_in[17];
  const float* out_b = (const float*)d_in[18];
  float* out = (float*)d_out;

  const int N = NN;
  const int E = in_sizes[1] / 2;

  char* ws = (char*)d_ws;
  size_t off = 0;
  auto alloc = [&](size_t bytes) -> char* {
    char* p = ws + off;
    off += (bytes + 255) & ~(size_t)255;
    return p;
  };
  ushort_t* h0 = (ushort_t*)alloc((size_t)N * 128 * 2);   // encoder out (bf16)
  ushort_t* hb = (ushort_t*)alloc((size_t)N * 128 * 2);   // scaled gather buffer (bf16)
  ushort_t* p1 = (ushort_t*)alloc((size_t)N * 128 * 2);   // branch-1 working / x1
  ushort_t* p2 = (ushort_t*)alloc((size_t)N * 128 * 2);   // branch-2 working / x2
  ushort_t* wpk[3];
  for (int l = 0; l < 3; ++l) wpk[l] = (ushort_t*)alloc(2048 * 8 * 2);  // 32 KB each

  struct G {
    int* deg; int* fill; float* dis; int* rp; int* bsum;
    int* csrc; const int* src; const int* dst;
  } g[2];
  for (int i = 0; i < 2; ++i) {
    g[i].deg = (int*)alloc((size_t)N * 4);
    g[i].fill = (int*)alloc((size_t)N * 4);
    g[i].dis = (float*)alloc((size_t)N * 4);
    g[i].rp = (int*)alloc((size_t)(N + 1) * 4);
    g[i].bsum = (int*)alloc(64 * 4);
    g[i].csrc = (int*)alloc((size_t)E * 4);
  }
  g[0].src = ei1; g[0].dst = ei1 + E;
  g[1].src = ei2; g[1].dst = ei2 + E;

  int nbScan = (N + 2047) / 2048;
  for (int i = 0; i < 2; ++i) {
    hipMemsetAsync(g[i].deg, 0, (size_t)N * 4, stream);
    hipMemsetAsync(g[i].fill, 0, (size_t)N * 4, stream);
    k_hist<<<(E + 255) / 256, 256, 0, stream>>>(g[i].dst, g[i].deg, E);
    k_dis<<<(N + 255) / 256, 256, 0, stream>>>(g[i].deg, g[i].dis, N);
    k_scanA<<<nbScan, 256, 0, stream>>>(g[i].deg, g[i].rp, g[i].bsum, N);
    k_scanB<<<1, 64, 0, stream>>>(g[i].bsum, nbScan);
    k_scanC<<<(N + 1 + 255) / 256, 256, 0, stream>>>(g[i].rp, g[i].bsum, N, E);
    k_fill<<<(E + 255) / 256, 256, 0, stream>>>(g[i].src, g[i].dst, g[i].rp, g[i].fill,
                                                g[i].csrc, E);
  }

  // pack conv weights to MFMA fragment order (bf16)
  for (int l = 0; l < 3; ++l) k_packw<<<8, 256, 0, stream>>>(conv_w[l], wpk[l]);

  int gb = (N + 63) / 64;
  // shared encoder -> h0 (bf16, preserved for both branches)
  k_gemm_enc<64><<<gb, 256, 0, stream>>>(x, enc_w, enc_b, h0, N);

  // branch 1: h0 -> ... -> x1 in p1
  {
    const ushort_t* cur = h0;
    for (int l = 0; l < 3; ++l) {
      k_gemm_mfma<<<gb, 256, 0, stream>>>(cur, wpk[l], g[0].dis, hb, N);
      k_agg<<<(N + 3) / 4, 256, 0, stream>>>((const uint_t*)hb, g[0].rp, g[0].csrc,
                                             g[0].dis, conv_b[l], ln_g[l], ln_b[l],
                                             (uint_t*)p1, N);
      cur = p1;
    }
  }
  // branch 2: h0 -> ... -> x2 in p2
  {
    const ushort_t* cur = h0;
    for (int l = 0; l < 3; ++l) {
      k_gemm_mfma<<<gb, 256, 0, stream>>>(cur, wpk[l], g[1].dis, hb, N);
      k_agg<<<(N + 3) / 4, 256, 0, stream>>>((const uint_t*)hb, g[1].rp, g[1].csrc,
                                             g[1].dis, conv_b[l], ln_g[l], ln_b[l],
                                             (uint_t*)p2, N);
      cur = p2;
    }
  }

  k_out<<<(N + 255) / 256, 256, 0, stream>>>(p1, p2, out_w, out_b, out, N);
}